// Round 1
// baseline (423.406 us; speedup 1.0000x reference)
//
#include <hip/hip_runtime.h>

typedef unsigned long long u64;

#define N_SP 3136          // 56*56
#define C_IN 256
#define C_OUT 256
#define BATCH 32
#define HT 8               // rows per conv wave-tile

// ---------------------------------------------------------------- zero stats
__global__ void zero_stats(u64* s) {
    s[threadIdx.x] = 0ull;   // 1 block x 512
}

// ---------------------------------------------------------------- weight prep
// One block per output channel o (256 threads = one per input channel).
// wc = w - mean_over_Cin; pack sign bits (bit j of word k = channel 64k+j > 0);
// alpha[o] = mean over 2304 of min(|wc|,1), in double.
__global__ __launch_bounds__(256) void prep_weights(const float* __restrict__ w,
                                                    u64* __restrict__ wbits,
                                                    double* __restrict__ alpha) {
    const int o = blockIdx.x;
    const int i = threadIdx.x;           // input channel
    const int lane = i & 63, wave = i >> 6;
    __shared__ double red[256];
    __shared__ double mean[9];

    float wv[9];
    const float* wp = w + ((size_t)o * C_IN + i) * 9;
#pragma unroll
    for (int t = 0; t < 9; ++t) wv[t] = wp[t];

    double asum = 0.0;
    for (int t = 0; t < 9; ++t) {
        red[i] = (double)wv[t];
        __syncthreads();
        for (int s = 128; s > 0; s >>= 1) {
            if (i < s) red[i] += red[i + s];
            __syncthreads();
        }
        if (i == 0) mean[t] = red[0] * (1.0 / 256.0);
        __syncthreads();
        double wc = (double)wv[t] - mean[t];
        u64 m = __ballot(wc > 0.0);
        if (lane == 0) wbits[((size_t)o * 9 + t) * 4 + wave] = m;
        double aw = fabs(wc);
        if (aw > 1.0) aw = 1.0;
        asum += aw;
        __syncthreads();   // before red reuse
    }
    red[i] = asum;
    __syncthreads();
    for (int s = 128; s > 0; s >>= 1) {
        if (i < s) red[i] += red[i + s];
        __syncthreads();
    }
    if (i == 0) alpha[o] = red[0] * (1.0 / 2304.0);
}

// ---------------------------------------------------------------- pack x signs
// thread -> (position, word). word k bit j = (x[b][64k+j][pos] > 0).
__global__ __launch_bounds__(256) void pack_x(const float* __restrict__ x,
                                              u64* __restrict__ xbits) {
    const int tid = blockIdx.x * 256 + threadIdx.x;   // 0 .. 401407
    const int pos = tid >> 2;                          // global position
    const int word = tid & 3;
    const int b = pos / N_SP;
    const int sp = pos - b * N_SP;
    const float* xp = x + ((size_t)b * C_IN + word * 64) * N_SP + sp;
    u64 m = 0;
#pragma unroll
    for (int j = 0; j < 64; ++j) {
        m |= (u64)(xp[(size_t)j * N_SP] > 0.0f) << j;
    }
    xbits[((size_t)pos << 2) + word] = m;
}

// ---------------------------------------------------------------- popcount conv
__device__ __forceinline__ void accrow(const u64* xr, const u64 Wr[3][4],
                                       int& Q0, int& Q1, int& Q2) {
    int q0 = 0, q1 = 0, q2 = 0;
#pragma unroll
    for (int k = 0; k < 4; ++k) {
        q0 += __popcll(xr[k] ^ Wr[0][k]);
        q1 += __popcll(xr[k] ^ Wr[1][k]);
        q2 += __popcll(xr[k] ^ Wr[2][k]);
    }
    Q0 += q0; Q1 += q1; Q2 += q2;
}

// grid: (224 spatial tiles = 32 b x 7 row-tiles, 64 channel groups), block 256.
// wave = one channel; lane = output column w (56 active of 64).
__global__ __launch_bounds__(256) void conv_popc(const u64* __restrict__ xbits,
                                                 const u64* __restrict__ wbits,
                                                 float* __restrict__ out,
                                                 u64* __restrict__ stats) {
    const int wave = threadIdx.x >> 6;
    const int lane = threadIdx.x & 63;
    const int tile = blockIdx.x;
    const int b = tile / 7;
    const int h0 = (tile % 7) * HT;
    const int c = (blockIdx.y << 2) + wave;
    const int w = lane;
    const bool active = (w < 56);
    const int wcl = active ? w : 55;

    // weights: 9 taps x 4 words
    u64 W[3][3][4];
    const u64* wp = wbits + (size_t)c * 36;
#pragma unroll
    for (int r = 0; r < 3; ++r)
#pragma unroll
        for (int kw = 0; kw < 3; ++kw)
#pragma unroll
            for (int k = 0; k < 4; ++k)
                W[r][kw][k] = wp[(r * 3 + kw) * 4 + k];

    const u64* xb = xbits + ((size_t)b * N_SP << 2);
    u64 a0[4] = {0, 0, 0, 0}, a1[4], a2[4];
    {
        const u64* p;
        if (h0 > 0) {
            p = xb + (((size_t)(h0 - 1) * 56 + wcl) << 2);
#pragma unroll
            for (int k = 0; k < 4; ++k) a0[k] = p[k];
        }
        p = xb + (((size_t)h0 * 56 + wcl) << 2);
#pragma unroll
        for (int k = 0; k < 4; ++k) a1[k] = p[k];
        p = xb + (((size_t)(h0 + 1) * 56 + wcl) << 2);
#pragma unroll
        for (int k = 0; k < 4; ++k) a2[k] = p[k];
    }

    int isum = 0;
    unsigned usq = 0;
    float* outc = out + ((size_t)b * C_OUT + c) * N_SP;
    const int vc = 3 - (w == 0) - (w == 55);

#pragma unroll
    for (int hh = 0; hh < HT; ++hh) {
        const int h = h0 + hh;
        int Q0 = 0, Q1 = 0, Q2 = 0;
        int nr = 1;
        if (h > 0)  { accrow(a0, W[0], Q0, Q1, Q2); nr++; }
        accrow(a1, W[1], Q0, Q1, Q2);
        if (h < 55) { accrow(a2, W[2], Q0, Q1, Q2); nr++; }
        if (!active) { Q0 = 0; Q1 = 0; Q2 = 0; }
        int L = __shfl_up(Q0, 1);
        if (lane == 0) L = 0;
        int R = __shfl_down(Q2, 1);        // lane 55 reads lane 56 (zeroed)
        int S = ((nr * vc) << 8) - ((L + Q1 + R) << 1);
        if (active) {
            outc[h * 56 + w] = (float)S;
            isum += S;
            usq += (unsigned)(S * S);
        }
        if (hh < HT - 1) {
#pragma unroll
            for (int k = 0; k < 4; ++k) { a0[k] = a1[k]; a1[k] = a2[k]; }
            if (h + 2 < 56) {
                const u64* p = xb + (((size_t)(h + 2) * 56 + wcl) << 2);
#pragma unroll
                for (int k = 0; k < 4; ++k) a2[k] = p[k];
            }
        }
    }

    // wave reduce (int / unsigned; max |isum| ~1e6, max usq ~2.4e9 < 2^32)
#pragma unroll
    for (int off = 32; off > 0; off >>= 1) {
        isum += __shfl_down(isum, off);
        usq += (unsigned)__shfl_down((int)usq, off);
    }
    if (lane == 0) {
        atomicAdd(&stats[c], (u64)(long long)isum);
        atomicAdd(&stats[C_OUT + c], (u64)usq);
    }
}

// ---------------------------------------------------------------- BN consts
__global__ void make_consts(const u64* __restrict__ stats,
                            const double* __restrict__ alpha,
                            const float* __restrict__ gamma,
                            const float* __restrict__ beta,
                            double* __restrict__ AB) {
    const int c = threadIdx.x;
    const double N = (double)(BATCH * N_SP);
    double s1 = (double)(long long)stats[c];
    double s2 = (double)(long long)stats[C_OUT + c];
    double mu = s1 / N;
    double var = s2 / N - mu * mu;
    double a = alpha[c];
    double vy = a * a * var;
    double scale = (double)gamma[c] / sqrt(vy + 1e-5);
    double A = a * scale;
    double B = (double)beta[c] - A * mu;
    AB[c] = A;
    AB[C_OUT + c] = B;
}

// ---------------------------------------------------------------- finalize
// In-place: d_out holds exact-integer S as float; out = (A*S+B > 0) ? 1 : 0.
__global__ __launch_bounds__(256) void finalize(float* __restrict__ out,
                                                const double* __restrict__ AB) {
    const unsigned i4 = blockIdx.x * 256 + threadIdx.x;   // 0 .. 6422527
    const unsigned e = i4 << 2;                            // element base
    const int c = (int)((e / N_SP) & (C_OUT - 1));         // 3136 | 4, so c uniform in float4
    const double A = AB[c];
    const double B = AB[C_OUT + c];
    float4 v = ((float4*)out)[i4];
    v.x = (A * (double)v.x + B) > 0.0 ? 1.0f : 0.0f;
    v.y = (A * (double)v.y + B) > 0.0 ? 1.0f : 0.0f;
    v.z = (A * (double)v.z + B) > 0.0 ? 1.0f : 0.0f;
    v.w = (A * (double)v.w + B) > 0.0 ? 1.0f : 0.0f;
    ((float4*)out)[i4] = v;
}

// ---------------------------------------------------------------- launch
extern "C" void kernel_launch(void* const* d_in, const int* in_sizes, int n_in,
                              void* d_out, int out_size, void* d_ws, size_t ws_size,
                              hipStream_t stream) {
    const float* x      = (const float*)d_in[0];
    const float* weight = (const float*)d_in[1];
    const float* bias   = (const float*)d_in[2];   (void)bias;  // cancels in BN
    const float* gamma  = (const float*)d_in[3];
    const float* beta   = (const float*)d_in[4];
    float* out = (float*)d_out;

    char* ws = (char*)d_ws;
    u64*    stats = (u64*)(ws);                 // [512]
    double* alpha = (double*)(ws + 4096);       // [256]
    double* AB    = (double*)(ws + 8192);       // [512]
    u64*    wbits = (u64*)(ws + 16384);         // [256*9*4]
    u64*    xbits = (u64*)(ws + 98304);         // [32*3136*4]

    zero_stats<<<1, 512, 0, stream>>>(stats);
    prep_weights<<<C_OUT, 256, 0, stream>>>(weight, wbits, alpha);
    pack_x<<<(BATCH * N_SP * 4) / 256, 256, 0, stream>>>(x, xbits);
    conv_popc<<<dim3(BATCH * 7, C_OUT / 4), 256, 0, stream>>>(xbits, wbits, out, stats);
    make_consts<<<1, C_OUT, 0, stream>>>(stats, alpha, gamma, beta, AB);
    finalize<<<(out_size / 4) / 256, 256, 0, stream>>>(out, AB);
}